// Round 4
// baseline (25128.668 us; speedup 1.0000x reference)
//
#include <hip/hip_runtime.h>

#define N_NODES   100000
#define N_EDGES   1000000
#define N_PAIRS   2000000
#define IN_CH     64
#define OUT_CH    64
#define NODE_DIM  37
#define STATE_DIM 5
#define FEAT_DIM  106   // IN_CH + NODE_DIM + STATE_DIM

__device__ __forceinline__ float elu_f(float s) {
    return s > 0.f ? s : expm1f(s);
}

// ---------------------------------------------------------------------------
// Round-2 lessons encoded here:
//  * W per-lane in VGPRs is structurally impossible: 106 live floats/lane
//    either get rematerialized as 64-line L1 scatters (VGPR=64, round 1) or
//    spilled to scratch when pinned (VGPR=112, round 2, -61%). So W lives in
//    LDS, TRANSPOSED: Wt[j][c]. Lane c reads word j*64+c -> 64 consecutive
//    words -> 2-way bank aliasing, which is free on gfx950 (m136). One
//    ds_read_b32 per j replaces a 64-cacheline divergent L1 gather, and is
//    reused across 4 pairs in flight.
//  * Kernel is latency-bound (VALUBusy 28%, HBM 14%): 4 pairs per wave-iter
//    doubles round-1's memory-level parallelism (that lever gave 1.37x).
// ---------------------------------------------------------------------------
__global__ __launch_bounds__(256, 4) void pair_kernel(
    const float* __restrict__ x,     // [N_NODES, 37]
    const float* __restrict__ gs,    // [N_NODES, 5]
    const float* __restrict__ ea,    // [N_EDGES, 64]
    const float* __restrict__ W,     // [64, 106]
    const float* __restrict__ b,     // [64]
    const int* __restrict__ aidx,    // [2, N_PAIRS]
    const int* __restrict__ eidx,    // [2, N_PAIRS]
    float* __restrict__ out)         // [N_EDGES, 64] — accumulated in place
{
    __shared__ float Wt[FEAT_DIM][OUT_CH];   // 27 KB, transposed W
    const int t = threadIdx.x;
    for (int i = t; i < FEAT_DIM * OUT_CH; i += 256) {  // coalesced fill
        const int c = i / FEAT_DIM;
        const int j = i - c * FEAT_DIM;
        Wt[j][c] = W[i];
    }
    __syncthreads();

    const int lane = t & 63;
    const int wave = t >> 6;
    const float bias = b[lane];

    const int gw  = blockIdx.x * 4 + wave;   // global wave id (uniform)
    const int gws = gridDim.x * 4;

    for (int k = gw * 4; k < N_PAIRS; k += gws * 4) {   // N_PAIRS % 4 == 0
        // ---- all 12 index loads up front (16B-aligned quads) ----
        const int sA = eidx[k + 0], sB = eidx[k + 1];
        const int sC = eidx[k + 2], sD = eidx[k + 3];
        const int eA = eidx[N_PAIRS + k + 0], eB = eidx[N_PAIRS + k + 1];
        const int eC = eidx[N_PAIRS + k + 2], eD = eidx[N_PAIRS + k + 3];
        const int aA = aidx[k + 0], aB = aidx[k + 1];
        const int aC = aidx[k + 2], aD = aidx[k + 3];

        const float4* pA = (const float4*)(ea + (size_t)eA * IN_CH);
        const float4* pB = (const float4*)(ea + (size_t)eB * IN_CH);
        const float4* pC = (const float4*)(ea + (size_t)eC * IN_CH);
        const float4* pD = (const float4*)(ea + (size_t)eD * IN_CH);
        const float* xA = x + (size_t)aA * NODE_DIM;
        const float* xB = x + (size_t)aB * NODE_DIM;
        const float* xC = x + (size_t)aC * NODE_DIM;
        const float* xD = x + (size_t)aD * NODE_DIM;
        const float* gA = gs + (size_t)aA * STATE_DIM;
        const float* gB = gs + (size_t)aB * STATE_DIM;
        const float* gC = gs + (size_t)aC * STATE_DIM;
        const float* gD = gs + (size_t)aD * STATE_DIM;

        float accA0 = bias, accA1 = 0.f;
        float accB0 = bias, accB1 = 0.f;
        float accC0 = bias, accC1 = 0.f;
        float accD0 = bias, accD1 = 0.f;

        #pragma unroll
        for (int q = 0; q < IN_CH / 4; ++q) {   // edge_attr part: 64 feats
            const float4 fA = pA[q];
            const float4 fB = pB[q];
            const float4 fC = pC[q];
            const float4 fD = pD[q];
            const float w0 = Wt[4 * q + 0][lane];
            const float w1 = Wt[4 * q + 1][lane];
            const float w2 = Wt[4 * q + 2][lane];
            const float w3 = Wt[4 * q + 3][lane];
            accA0 = fmaf(w0, fA.x, accA0); accA1 = fmaf(w1, fA.y, accA1);
            accA0 = fmaf(w2, fA.z, accA0); accA1 = fmaf(w3, fA.w, accA1);
            accB0 = fmaf(w0, fB.x, accB0); accB1 = fmaf(w1, fB.y, accB1);
            accB0 = fmaf(w2, fB.z, accB0); accB1 = fmaf(w3, fB.w, accB1);
            accC0 = fmaf(w0, fC.x, accC0); accC1 = fmaf(w1, fC.y, accC1);
            accC0 = fmaf(w2, fC.z, accC0); accC1 = fmaf(w3, fC.w, accC1);
            accD0 = fmaf(w0, fD.x, accD0); accD1 = fmaf(w1, fD.y, accD1);
            accD0 = fmaf(w2, fD.z, accD0); accD1 = fmaf(w3, fD.w, accD1);
        }
        #pragma unroll
        for (int j = 0; j < 36; j += 4) {       // node features 0..35
            const float w0 = Wt[IN_CH + j + 0][lane];
            const float w1 = Wt[IN_CH + j + 1][lane];
            const float w2 = Wt[IN_CH + j + 2][lane];
            const float w3 = Wt[IN_CH + j + 3][lane];
            accA0 = fmaf(w0, xA[j + 0], accA0); accA1 = fmaf(w1, xA[j + 1], accA1);
            accA0 = fmaf(w2, xA[j + 2], accA0); accA1 = fmaf(w3, xA[j + 3], accA1);
            accB0 = fmaf(w0, xB[j + 0], accB0); accB1 = fmaf(w1, xB[j + 1], accB1);
            accB0 = fmaf(w2, xB[j + 2], accB0); accB1 = fmaf(w3, xB[j + 3], accB1);
            accC0 = fmaf(w0, xC[j + 0], accC0); accC1 = fmaf(w1, xC[j + 1], accC1);
            accC0 = fmaf(w2, xC[j + 2], accC0); accC1 = fmaf(w3, xC[j + 3], accC1);
            accD0 = fmaf(w0, xD[j + 0], accD0); accD1 = fmaf(w1, xD[j + 1], accD1);
            accD0 = fmaf(w2, xD[j + 2], accD0); accD1 = fmaf(w3, xD[j + 3], accD1);
        }
        {                                       // node feature 36
            const float w36 = Wt[IN_CH + 36][lane];
            accA0 = fmaf(w36, xA[36], accA0);
            accB0 = fmaf(w36, xB[36], accB0);
            accC0 = fmaf(w36, xC[36], accC0);
            accD0 = fmaf(w36, xD[36], accD0);
        }
        #pragma unroll
        for (int j = 0; j < STATE_DIM; ++j) {   // global state, 5 feats
            const float w = Wt[IN_CH + NODE_DIM + j][lane];
            accA1 = fmaf(w, gA[j], accA1);
            accB1 = fmaf(w, gB[j], accB1);
            accC1 = fmaf(w, gC[j], accC1);
            accD1 = fmaf(w, gD[j], accD1);
        }

        const float hA = elu_f(accA0 + accA1);
        const float hB = elu_f(accB0 + accB1);
        const float hC = elu_f(accC0 + accC1);
        const float hD = elu_f(accD0 + accD1);
        atomicAdd(&out[(size_t)sA * OUT_CH + lane], hA);
        atomicAdd(&out[(size_t)sB * OUT_CH + lane], hB);
        atomicAdd(&out[(size_t)sC * OUT_CH + lane], hC);
        atomicAdd(&out[(size_t)sD * OUT_CH + lane], hD);
    }
}

// ---------------------------------------------------------------------------
// Stage 1: out[e][c] = elu(W_e[c].edge_attr[e] + b_e[c]). Same LDS-W +
// 4-edge-ILP structure (round-1 version was ~750us vs an ~85us stream floor,
// same latency disease). Runs first; pair_kernel accumulates on top.
// ---------------------------------------------------------------------------
__global__ __launch_bounds__(256, 4) void base_kernel(
    const float* __restrict__ ea,    // [N_EDGES, 64]
    const float* __restrict__ We,    // [64, 64]
    const float* __restrict__ be,    // [64]
    float* __restrict__ out)         // [N_EDGES, 64]
{
    __shared__ float Wt[IN_CH][OUT_CH];      // 16 KB, transposed We
    const int t = threadIdx.x;
    for (int i = t; i < IN_CH * OUT_CH; i += 256) {
        const int c = i >> 6;
        const int j = i & 63;
        Wt[j][c] = We[i];
    }
    __syncthreads();

    const int lane = t & 63;
    const int wave = t >> 6;
    const float bias = be[lane];

    const int gw  = blockIdx.x * 4 + wave;
    const int gws = gridDim.x * 4;

    for (int e = gw * 4; e < N_EDGES; e += gws * 4) {   // N_EDGES % 4 == 0
        const float4* pA = (const float4*)(ea + (size_t)(e + 0) * IN_CH);
        const float4* pB = (const float4*)(ea + (size_t)(e + 1) * IN_CH);
        const float4* pC = (const float4*)(ea + (size_t)(e + 2) * IN_CH);
        const float4* pD = (const float4*)(ea + (size_t)(e + 3) * IN_CH);

        float accA0 = bias, accA1 = 0.f;
        float accB0 = bias, accB1 = 0.f;
        float accC0 = bias, accC1 = 0.f;
        float accD0 = bias, accD1 = 0.f;

        #pragma unroll
        for (int q = 0; q < IN_CH / 4; ++q) {
            const float4 fA = pA[q];
            const float4 fB = pB[q];
            const float4 fC = pC[q];
            const float4 fD = pD[q];
            const float w0 = Wt[4 * q + 0][lane];
            const float w1 = Wt[4 * q + 1][lane];
            const float w2 = Wt[4 * q + 2][lane];
            const float w3 = Wt[4 * q + 3][lane];
            accA0 = fmaf(w0, fA.x, accA0); accA1 = fmaf(w1, fA.y, accA1);
            accA0 = fmaf(w2, fA.z, accA0); accA1 = fmaf(w3, fA.w, accA1);
            accB0 = fmaf(w0, fB.x, accB0); accB1 = fmaf(w1, fB.y, accB1);
            accB0 = fmaf(w2, fB.z, accB0); accB1 = fmaf(w3, fB.w, accB1);
            accC0 = fmaf(w0, fC.x, accC0); accC1 = fmaf(w1, fC.y, accC1);
            accC0 = fmaf(w2, fC.z, accC0); accC1 = fmaf(w3, fC.w, accC1);
            accD0 = fmaf(w0, fD.x, accD0); accD1 = fmaf(w1, fD.y, accD1);
            accD0 = fmaf(w2, fD.z, accD0); accD1 = fmaf(w3, fD.w, accD1);
        }
        out[(size_t)(e + 0) * OUT_CH + lane] = elu_f(accA0 + accA1);
        out[(size_t)(e + 1) * OUT_CH + lane] = elu_f(accB0 + accB1);
        out[(size_t)(e + 2) * OUT_CH + lane] = elu_f(accC0 + accC1);
        out[(size_t)(e + 3) * OUT_CH + lane] = elu_f(accD0 + accD1);
    }
}

extern "C" void kernel_launch(void* const* d_in, const int* in_sizes, int n_in,
                              void* d_out, int out_size, void* d_ws, size_t ws_size,
                              hipStream_t stream) {
    const float* x    = (const float*)d_in[0];
    const float* gs   = (const float*)d_in[1];
    const float* ea   = (const float*)d_in[2];
    const float* W    = (const float*)d_in[3];
    const float* b    = (const float*)d_in[4];
    const float* We   = (const float*)d_in[5];
    const float* be   = (const float*)d_in[6];
    const int*   aidx = (const int*)d_in[7];
    const int*   eidx = (const int*)d_in[8];
    float* out = (float*)d_out;

    base_kernel<<<2048, 256, 0, stream>>>(ea, We, be, out);
    pair_kernel<<<2048, 256, 0, stream>>>(x, gs, ea, W, b, aidx, eidx, out);
}

// Round 5
// 9820.557 us; speedup vs baseline: 2.5588x; 2.5588x over previous
//
#include <hip/hip_runtime.h>

#define N_NODES   100000
#define N_EDGES   1000000
#define N_PAIRS   2000000
#define IN_CH     64
#define OUT_CH    64
#define NODE_DIM  37
#define STATE_DIM 5
#define FEAT_DIM  106   // IN_CH + NODE_DIM + STATE_DIM

__device__ __forceinline__ float elu_f(float s) {
    return s > 0.f ? s : expm1f(s);
}

// Opaque zero in a VGPR. Adding it to a base pointer makes every derived
// address VGPR-resident, so the compiler MUST emit vector global_load
// (vmcnt) instead of scalarizing wave-uniform loads to s_load (lgkmcnt).
// Round-4 evidence: mixing s_load feat fetches with ds_read W fetches on the
// shared lgkmcnt counter forces full lgkmcnt(0) drains (SMEM is unordered),
// serializing each iteration; base_kernel regressed 750us -> 3.6ms from this
// alone. With feat on vmcnt, ds_reads get precise counted lgkmcnt waits.
#define OPAQUE_VGPR_ZERO(v) asm volatile("v_mov_b32 %0, 0" : "=v"(v))

// ---------------------------------------------------------------------------
// pair_kernel: one wave per pair, 2 pairs per iteration (round-1's proven
// 64-VGPR register shape; round-4's 4-pair variant spilled ~60GB of scratch).
// W lives in LDS TRANSPOSED: Wt[j][c] -> lane c reads word j*64+c, 64
// consecutive words = 2-way bank aliasing = free (m136). One ds_read_b32 per
// j replaces round-1's 64-cacheline divergent L1 gather of W[lane*106+j].
// ---------------------------------------------------------------------------
__global__ __launch_bounds__(256, 2) void pair_kernel(
    const float* __restrict__ x,     // [N_NODES, 37]
    const float* __restrict__ gs,    // [N_NODES, 5]
    const float* __restrict__ ea,    // [N_EDGES, 64]
    const float* __restrict__ W,     // [64, 106]
    const float* __restrict__ b,     // [64]
    const int* __restrict__ aidx,    // [2, N_PAIRS]
    const int* __restrict__ eidx,    // [2, N_PAIRS]
    float* __restrict__ out)         // [N_EDGES, 64] — accumulated in place
{
    __shared__ float Wt[FEAT_DIM][OUT_CH];   // 27 KB, transposed W
    const int t = threadIdx.x;
    for (int i = t; i < FEAT_DIM * OUT_CH; i += 256) {  // once per block
        const int c = i / FEAT_DIM;
        const int j = i - c * FEAT_DIM;
        Wt[j][c] = W[i];
    }
    __syncthreads();

    int vz;
    OPAQUE_VGPR_ZERO(vz);
    // Poisoned bases: every load below goes through these -> VMEM path.
    const float* xv  = (const float*)((const char*)x    + vz);
    const float* gv  = (const float*)((const char*)gs   + vz);
    const float* ev  = (const float*)((const char*)ea   + vz);
    const int*   av  = (const int*)  ((const char*)aidx + vz);
    const int*   iv  = (const int*)  ((const char*)eidx + vz);

    const int lane = t & 63;
    const int wave = __builtin_amdgcn_readfirstlane(t >> 6);
    const float bias = b[lane];

    const int gw  = blockIdx.x * 4 + wave;   // global wave id (uniform)
    const int gws = gridDim.x * 4;

    for (int k = gw * 2; k < N_PAIRS; k += gws * 2) {   // N_PAIRS even
        // ---- 6 index loads up front (adjacent pairs merge to dwordx2) ----
        const int sA = iv[k],           sB = iv[k + 1];           // e_idx[0]
        const int eA = iv[N_PAIRS + k], eB = iv[N_PAIRS + k + 1]; // e_idx[1]
        const int aA = av[k],           aB = av[k + 1];           // atom[0]

        const float4* pA = (const float4*)(ev + (size_t)eA * IN_CH);
        const float4* pB = (const float4*)(ev + (size_t)eB * IN_CH);
        const float*  xA = xv + (size_t)aA * NODE_DIM;
        const float*  xB = xv + (size_t)aB * NODE_DIM;
        const float*  gA = gv + (size_t)aA * STATE_DIM;
        const float*  gB = gv + (size_t)aB * STATE_DIM;

        float accA0 = bias, accA1 = 0.f;
        float accB0 = bias, accB1 = 0.f;

        #pragma unroll
        for (int q = 0; q < IN_CH / 4; ++q) {   // edge_attr part: 64 feats
            const float4 fA = pA[q];
            const float4 fB = pB[q];
            const float w0 = Wt[4 * q + 0][lane];
            const float w1 = Wt[4 * q + 1][lane];
            const float w2 = Wt[4 * q + 2][lane];
            const float w3 = Wt[4 * q + 3][lane];
            accA0 = fmaf(w0, fA.x, accA0); accA1 = fmaf(w1, fA.y, accA1);
            accA0 = fmaf(w2, fA.z, accA0); accA1 = fmaf(w3, fA.w, accA1);
            accB0 = fmaf(w0, fB.x, accB0); accB1 = fmaf(w1, fB.y, accB1);
            accB0 = fmaf(w2, fB.z, accB0); accB1 = fmaf(w3, fB.w, accB1);
        }
        #pragma unroll
        for (int j = 0; j < 36; j += 4) {       // node features 0..35
            const float w0 = Wt[IN_CH + j + 0][lane];
            const float w1 = Wt[IN_CH + j + 1][lane];
            const float w2 = Wt[IN_CH + j + 2][lane];
            const float w3 = Wt[IN_CH + j + 3][lane];
            accA0 = fmaf(w0, xA[j + 0], accA0); accA1 = fmaf(w1, xA[j + 1], accA1);
            accA0 = fmaf(w2, xA[j + 2], accA0); accA1 = fmaf(w3, xA[j + 3], accA1);
            accB0 = fmaf(w0, xB[j + 0], accB0); accB1 = fmaf(w1, xB[j + 1], accB1);
            accB0 = fmaf(w2, xB[j + 2], accB0); accB1 = fmaf(w3, xB[j + 3], accB1);
        }
        {                                       // node feature 36
            const float w36 = Wt[IN_CH + 36][lane];
            accA0 = fmaf(w36, xA[36], accA0);
            accB0 = fmaf(w36, xB[36], accB0);
        }
        #pragma unroll
        for (int j = 0; j < STATE_DIM; ++j) {   // global state, 5 feats
            const float w = Wt[IN_CH + NODE_DIM + j][lane];
            accA1 = fmaf(w, gA[j], accA1);
            accB1 = fmaf(w, gB[j], accB1);
        }

        const float hA = elu_f(accA0 + accA1);
        const float hB = elu_f(accB0 + accB1);
        atomicAdd(&out[(size_t)sA * OUT_CH + lane], hA);
        atomicAdd(&out[(size_t)sB * OUT_CH + lane], hB);
    }
}

// ---------------------------------------------------------------------------
// Stage 1: out[e][c] = elu(W_e[c].edge_attr[e] + b_e[c]). LDS-W + VMEM-forced
// feat loads. 4 consecutive edges per iteration: all 64 feat loads fold to
// one base address + immediate offsets (13-bit signed imm covers 4*256B),
// so register demand stays ~40. Runs first; pair_kernel accumulates on top.
// ---------------------------------------------------------------------------
__global__ __launch_bounds__(256, 2) void base_kernel(
    const float* __restrict__ ea,    // [N_EDGES, 64]
    const float* __restrict__ We,    // [64, 64]
    const float* __restrict__ be,    // [64]
    float* __restrict__ out)         // [N_EDGES, 64]
{
    __shared__ float Wt[IN_CH][OUT_CH];      // 16 KB, transposed We
    const int t = threadIdx.x;
    for (int i = t; i < IN_CH * OUT_CH; i += 256) {
        const int c = i >> 6;
        const int j = i & 63;
        Wt[j][c] = We[i];
    }
    __syncthreads();

    int vz;
    OPAQUE_VGPR_ZERO(vz);
    const float* ev = (const float*)((const char*)ea + vz);

    const int lane = t & 63;
    const int wave = __builtin_amdgcn_readfirstlane(t >> 6);
    const float bias = be[lane];

    const int gw  = blockIdx.x * 4 + wave;
    const int gws = gridDim.x * 4;

    for (int e = gw * 4; e < N_EDGES; e += gws * 4) {   // N_EDGES % 4 == 0
        const float4* p = (const float4*)(ev + (size_t)e * IN_CH);

        float accA0 = bias, accA1 = 0.f;
        float accB0 = bias, accB1 = 0.f;
        float accC0 = bias, accC1 = 0.f;
        float accD0 = bias, accD1 = 0.f;

        #pragma unroll
        for (int q = 0; q < IN_CH / 4; ++q) {
            const float4 fA = p[q];          // edge e     (imm offset)
            const float4 fB = p[16 + q];     // edge e+1
            const float4 fC = p[32 + q];     // edge e+2
            const float4 fD = p[48 + q];     // edge e+3
            const float w0 = Wt[4 * q + 0][lane];
            const float w1 = Wt[4 * q + 1][lane];
            const float w2 = Wt[4 * q + 2][lane];
            const float w3 = Wt[4 * q + 3][lane];
            accA0 = fmaf(w0, fA.x, accA0); accA1 = fmaf(w1, fA.y, accA1);
            accA0 = fmaf(w2, fA.z, accA0); accA1 = fmaf(w3, fA.w, accA1);
            accB0 = fmaf(w0, fB.x, accB0); accB1 = fmaf(w1, fB.y, accB1);
            accB0 = fmaf(w2, fB.z, accB0); accB1 = fmaf(w3, fB.w, accB1);
            accC0 = fmaf(w0, fC.x, accC0); accC1 = fmaf(w1, fC.y, accC1);
            accC0 = fmaf(w2, fC.z, accC0); accC1 = fmaf(w3, fC.w, accC1);
            accD0 = fmaf(w0, fD.x, accD0); accD1 = fmaf(w1, fD.y, accD1);
            accD0 = fmaf(w2, fD.z, accD0); accD1 = fmaf(w3, fD.w, accD1);
        }
        out[(size_t)(e + 0) * OUT_CH + lane] = elu_f(accA0 + accA1);
        out[(size_t)(e + 1) * OUT_CH + lane] = elu_f(accB0 + accB1);
        out[(size_t)(e + 2) * OUT_CH + lane] = elu_f(accC0 + accC1);
        out[(size_t)(e + 3) * OUT_CH + lane] = elu_f(accD0 + accD1);
    }
}

extern "C" void kernel_launch(void* const* d_in, const int* in_sizes, int n_in,
                              void* d_out, int out_size, void* d_ws, size_t ws_size,
                              hipStream_t stream) {
    const float* x    = (const float*)d_in[0];
    const float* gs   = (const float*)d_in[1];
    const float* ea   = (const float*)d_in[2];
    const float* W    = (const float*)d_in[3];
    const float* b    = (const float*)d_in[4];
    const float* We   = (const float*)d_in[5];
    const float* be   = (const float*)d_in[6];
    const int*   aidx = (const int*)d_in[7];
    const int*   eidx = (const int*)d_in[8];
    float* out = (float*)d_out;

    base_kernel<<<2048, 256, 0, stream>>>(ea, We, be, out);
    pair_kernel<<<2048, 256, 0, stream>>>(x, gs, ea, W, b, aidx, eidx, out);
}

// Round 6
// 7465.041 us; speedup vs baseline: 3.3662x; 1.3155x over previous
//
#include <hip/hip_runtime.h>

#define N_NODES   100000
#define N_EDGES   1000000
#define N_PAIRS   2000000
#define IN_CH     64
#define OUT_CH    64
#define NODE_DIM  37
#define STATE_DIM 5
#define FEAT_DIM  106   // IN_CH + NODE_DIM + STATE_DIM

__device__ __forceinline__ float elu_f(float s) {
    return s > 0.f ? s : expm1f(s);
}

// ---------------------------------------------------------------------------
// FLIPPED decomposition (round-5 lesson): lane = PAIR, channels iterated.
//  * W[c][j] is wave-uniform -> scalar K$ s_load path, SGPR FMA operand.
//    No per-pair W cost (the structural limit of every lane=channel variant).
//  * lgkmcnt has NO other users (zero LDS) -> counted waits stay precise
//    (round-4 lesson: never mix ds_read with s_load).
//  * Feat loads are genuinely divergent row gathers (64 distinct rows per
//    instruction) -> normal coalescer gather, lines fully consumed. No
//    uniform-address VMEM micro-loads (round-5 lesson: those amplified
//    L2 fetch 12x via unmerged same-line misses).
//  * Channels in 4 chunks of 16: acc[16] statically indexed (VGPR ~45,
//    no spill - rounds 2/4 lesson), live W SGPRs ~64 < 102.
// ---------------------------------------------------------------------------
__global__ __launch_bounds__(256, 4) void pair_kernel(
    const float* __restrict__ x,     // [N_NODES, 37]
    const float* __restrict__ gs,    // [N_NODES, 5]
    const float* __restrict__ ea,    // [N_EDGES, 64]
    const float* __restrict__ W,     // [64, 106]
    const float* __restrict__ b,     // [64]
    const int* __restrict__ aidx,    // [2, N_PAIRS]
    const int* __restrict__ eidx,    // [2, N_PAIRS]
    float* __restrict__ out)         // [N_EDGES, 64] — accumulated in place
{
    const int t    = threadIdx.x;
    const int lane = t & 63;
    const int wid  = blockIdx.x * 4 + (t >> 6);   // global wave id
    const int nw   = gridDim.x * 4;

    for (int base = wid * 64; base < N_PAIRS; base += nw * 64) {
        const int  k     = base + lane;           // this lane's pair
        const bool valid = k < N_PAIRS;
        const int  kc    = valid ? k : N_PAIRS - 1;   // safe clamp

        const int seg = eidx[kc];                 // e_idx[0][k]
        const int e2  = eidx[N_PAIRS + kc];       // e_idx[1][k]
        const int a0  = aidx[kc];                 // atom_index[0][k]

        const float* er = ea + (size_t)e2 * IN_CH;     // 256B-aligned row
        const float* xr = x  + (size_t)a0 * NODE_DIM;  // 4B-aligned row
        const float* gr = gs + (size_t)a0 * STATE_DIM;

        #pragma unroll 1
        for (int c0 = 0; c0 < OUT_CH; c0 += 16) {      // 4 channel chunks
            float acc[16];
            #pragma unroll
            for (int cc = 0; cc < 16; ++cc)
                acc[cc] = b[c0 + cc];                   // uniform s_load

            // ---- edge_attr part: feat[0..63], 16 aligned float4 windows ----
            #pragma unroll
            for (int jw = 0; jw < IN_CH / 4; ++jw) {
                const float4 f = *(const float4*)(er + jw * 4);
                #pragma unroll
                for (int cc = 0; cc < 16; ++cc) {
                    const float* wr = W + (size_t)(c0 + cc) * FEAT_DIM + jw * 4;
                    acc[cc] = fmaf(f.x, wr[0], acc[cc]);
                    acc[cc] = fmaf(f.y, wr[1], acc[cc]);
                    acc[cc] = fmaf(f.z, wr[2], acc[cc]);
                    acc[cc] = fmaf(f.w, wr[3], acc[cc]);
                }
            }
            // ---- node part: feat[64..99] = x[0..35], 9 windows of 4 ----
            #pragma unroll
            for (int jw = 0; jw < 9; ++jw) {
                const float f0 = xr[jw * 4 + 0];
                const float f1 = xr[jw * 4 + 1];
                const float f2 = xr[jw * 4 + 2];
                const float f3 = xr[jw * 4 + 3];
                #pragma unroll
                for (int cc = 0; cc < 16; ++cc) {
                    const float* wr = W + (size_t)(c0 + cc) * FEAT_DIM + IN_CH + jw * 4;
                    acc[cc] = fmaf(f0, wr[0], acc[cc]);
                    acc[cc] = fmaf(f1, wr[1], acc[cc]);
                    acc[cc] = fmaf(f2, wr[2], acc[cc]);
                    acc[cc] = fmaf(f3, wr[3], acc[cc]);
                }
            }
            // ---- tail: feat[100] = x[36], feat[101..105] = gs[0..4] ----
            {
                const float f0 = xr[36];
                const float g0 = gr[0], g1 = gr[1], g2 = gr[2];
                const float g3 = gr[3], g4 = gr[4];
                #pragma unroll
                for (int cc = 0; cc < 16; ++cc) {
                    const float* wr = W + (size_t)(c0 + cc) * FEAT_DIM + 100;
                    acc[cc] = fmaf(f0, wr[0], acc[cc]);
                    acc[cc] = fmaf(g0, wr[1], acc[cc]);
                    acc[cc] = fmaf(g1, wr[2], acc[cc]);
                    acc[cc] = fmaf(g2, wr[3], acc[cc]);
                    acc[cc] = fmaf(g3, wr[4], acc[cc]);
                    acc[cc] = fmaf(g4, wr[5], acc[cc]);
                }
            }

            if (valid) {
                #pragma unroll
                for (int cc = 0; cc < 16; ++cc)
                    atomicAdd(&out[(size_t)seg * OUT_CH + c0 + cc],
                              elu_f(acc[cc]));
            }
        }
    }
}

// ---------------------------------------------------------------------------
// Stage 1, same flip: lane = edge, We wave-uniform via K$/SGPR, plain stores.
// Runs first; pair_kernel atomicAdds segment sums on top (stream-ordered).
// ---------------------------------------------------------------------------
__global__ __launch_bounds__(256, 4) void base_kernel(
    const float* __restrict__ ea,    // [N_EDGES, 64]
    const float* __restrict__ We,    // [64, 64]
    const float* __restrict__ be,    // [64]
    float* __restrict__ out)         // [N_EDGES, 64]
{
    const int t    = threadIdx.x;
    const int lane = t & 63;
    const int wid  = blockIdx.x * 4 + (t >> 6);
    const int nw   = gridDim.x * 4;

    for (int base = wid * 64; base < N_EDGES; base += nw * 64) {
        const int  e     = base + lane;
        const bool valid = e < N_EDGES;
        const int  ec    = valid ? e : N_EDGES - 1;
        const float* er  = ea + (size_t)ec * IN_CH;

        #pragma unroll 1
        for (int c0 = 0; c0 < OUT_CH; c0 += 16) {
            float acc[16];
            #pragma unroll
            for (int cc = 0; cc < 16; ++cc)
                acc[cc] = be[c0 + cc];

            #pragma unroll
            for (int jw = 0; jw < IN_CH / 4; ++jw) {
                const float4 f = *(const float4*)(er + jw * 4);
                #pragma unroll
                for (int cc = 0; cc < 16; ++cc) {
                    const float* wr = We + (size_t)(c0 + cc) * IN_CH + jw * 4;
                    acc[cc] = fmaf(f.x, wr[0], acc[cc]);
                    acc[cc] = fmaf(f.y, wr[1], acc[cc]);
                    acc[cc] = fmaf(f.z, wr[2], acc[cc]);
                    acc[cc] = fmaf(f.w, wr[3], acc[cc]);
                }
            }
            if (valid) {
                #pragma unroll
                for (int cc = 0; cc < 16; ++cc)
                    out[(size_t)e * OUT_CH + c0 + cc] = elu_f(acc[cc]);
            }
        }
    }
}

extern "C" void kernel_launch(void* const* d_in, const int* in_sizes, int n_in,
                              void* d_out, int out_size, void* d_ws, size_t ws_size,
                              hipStream_t stream) {
    const float* x    = (const float*)d_in[0];
    const float* gs   = (const float*)d_in[1];
    const float* ea   = (const float*)d_in[2];
    const float* W    = (const float*)d_in[3];
    const float* b    = (const float*)d_in[4];
    const float* We   = (const float*)d_in[5];
    const float* be   = (const float*)d_in[6];
    const int*   aidx = (const int*)d_in[7];
    const int*   eidx = (const int*)d_in[8];
    float* out = (float*)d_out;

    base_kernel<<<2048, 256, 0, stream>>>(ea, We, be, out);
    pair_kernel<<<2048, 256, 0, stream>>>(x, gs, ea, W, b, aidx, eidx, out);
}